// Round 2
// baseline (343.633 us; speedup 1.0000x reference)
//
#include <hip/hip_runtime.h>
#include <math.h>

// x: [B,1,W,F] fp32, weights0: [F] fp32
// out: [B,1,2W-1,F] fp32; even rows = x[i], odd rows = s*x[i] + (1-s)*x[i+1],
// s = sigmoid(weights0).
//
// Layout facts: F = 256 floats = 64 float4 -> ONE WAVE (64 lanes) == one output
// row. tid directly indexes the output float4 array (out4[tid]), so stores are
// perfectly coalesced. The even/odd branch is wave-uniform. Stateless: every
// thread recomputes everything from (tid) alone — no carried registers, no
// cross-iteration state, no chunk-boundary overlap logic.
constexpr int B  = 16;
constexpr int W  = 8192;
constexpr int F  = 256;
constexpr int F4 = F / 4;          // 64 float4 per row == one wave
constexpr int OW = 2 * W - 1;      // 16383 output rows per batch

constexpr int TOTAL_F4 = B * OW * F4;   // 16,776,192 output float4 == thread count
constexpr int BLOCK    = 256;
constexpr int GRID     = TOTAL_F4 / BLOCK;  // 65,532 (divides exactly)

__global__ __launch_bounds__(BLOCK) void upsampler_kernel(
    const float4* __restrict__ x4,
    const float*  __restrict__ w0,
    float4* __restrict__ out4)
{
    const unsigned tid  = blockIdx.x * BLOCK + threadIdx.x;
    const unsigned lane = tid & 63u;          // float4 column within the row
    const unsigned rg   = tid >> 6;           // global output row, 0 .. B*OW-1
    const unsigned b    = rg / (unsigned)OW;  // batch  (magic-mul division)
    const unsigned row  = rg - b * (unsigned)OW;

    const float4* xb = x4 + (size_t)b * W * F4;

    float4 v;
    if ((row & 1u) == 0u) {
        // even output row 2i -> x[i]
        v = xb[(size_t)(row >> 1) * F4 + lane];
    } else {
        // odd output row 2i+1 -> s*x[i] + (1-s)*x[i+1]
        // row is odd => row <= 16381 => i+1 <= 8191 < W always (no guard).
        const unsigned i = row >> 1;
        const float4 a = xb[(size_t)i       * F4 + lane];
        const float4 c = xb[(size_t)(i + 1) * F4 + lane];
        const float4 wv = ((const float4*)w0)[lane];
        float4 s;
        s.x = 1.0f / (1.0f + expf(-wv.x));
        s.y = 1.0f / (1.0f + expf(-wv.y));
        s.z = 1.0f / (1.0f + expf(-wv.z));
        s.w = 1.0f / (1.0f + expf(-wv.w));
        v.x = s.x * a.x + (1.0f - s.x) * c.x;
        v.y = s.y * a.y + (1.0f - s.y) * c.y;
        v.z = s.z * a.z + (1.0f - s.z) * c.z;
        v.w = s.w * a.w + (1.0f - s.w) * c.w;
    }
    out4[tid] = v;   // out index == tid: fully contiguous coalesced store
}

extern "C" void kernel_launch(void* const* d_in, const int* in_sizes, int n_in,
                              void* d_out, int out_size, void* d_ws, size_t ws_size,
                              hipStream_t stream) {
    const float* x  = (const float*)d_in[0];   // [B,1,W,F] fp32
    const float* w0 = (const float*)d_in[1];   // [F] fp32
    float* out = (float*)d_out;                // [B,1,2W-1,F] fp32

    upsampler_kernel<<<GRID, BLOCK, 0, stream>>>(
        (const float4*)x, w0, (float4*)out);
}